// Round 4
// baseline (491.187 us; speedup 1.0000x reference)
//
#include <hip/hip_runtime.h>
#include <math.h>

// Circular 3D cross-correlation via FFT, B=8, V=128.
// Z = v1 + i*v2 packed complex FFT; Hermitian split; G = F1*conj(F2); inverse.
// Storage: each transformed axis in bit-reversed order (DIF fwd, DIT inv);
// combine pairs k<->-k via bitrev7 per axis (same convention as rounds 1-3).
//
// Round-4: occupancy. K1 splits the first x-stage across blocks (64-pt FFT
// halves, 66.5 KiB LDS -> 2 blocks/CU, no redundant compute). K2 uses
// y-quarter tiles (negrev maps quarters 0->0, 1->1, 2<->3) -> 67.6 KiB ->
// 2 blocks/CU. K3 packs two z-planes into one complex 2D inverse (each
// slice's inverse is real by 2D Hermitian symmetry) -> half the work.

#define V    128
#define V2   16384
#define V3   2097152
#define NB   8
#define PQ   33           // LDS pitch (float2) for 128x32 quarter tiles
#define TILEQ (V * PQ)    // 4224

__device__ __forceinline__ int bitrev7(int x) {
  return (int)(__brev((unsigned)x) >> 25);
}
__device__ __forceinline__ int negrev(int j) {
  int k = bitrev7(j);
  return bitrev7((V - k) & (V - 1));
}

__device__ __forceinline__ float2 cmul(float2 a, float2 b) {
  return make_float2(a.x * b.x - a.y * b.y, a.x * b.y + a.y * b.x);
}
__device__ __forceinline__ float2 f2add(float2 a, float2 b) {
  return make_float2(a.x + b.x, a.y + b.y);
}
__device__ __forceinline__ float2 f2sub(float2 a, float2 b) {
  return make_float2(a.x - b.x, a.y - b.y);
}
__device__ __forceinline__ float2 shflx(float2 v, int m) {
  return make_float2(__shfl_xor(v.x, m, 64), __shfl_xor(v.y, m, 64));
}

// 128-pt radix-2 FFT: 32 lanes/line, lane ll holds {ll, ll+32, ll+64, ll+96}.
// Fwd DIF (natural->bitrev): radix-4 head in-lane, 5 cross stages (mask<=16).
// Inv DIT (bitrev->natural): mirrored. Twiddles = per-lane constants.
template <bool INV>
struct WF128 {
  float2 wA, wB, w32, ts[5];
  float  sg[5];
  int    ll;

  __device__ void init(int lane) {
    ll = lane & 31;
    const float k = -6.28318530717958647692f / 128.0f;
    const float ca = cosf(k * (float)ll), sa = sinf(k * (float)ll);
    const float c2 = cosf(k * (float)(2 * ll)), s2 = sinf(k * (float)(2 * ll));
    if (!INV) {
      wA = make_float2(ca, sa);          // W128^ll
      wB = make_float2(sa, -ca);         // W128^ll * (-i)
      w32 = make_float2(c2, s2);         // W64^ll
    } else {
      wA = make_float2(ca, -sa);
      wB = make_float2(sa, ca);
      w32 = make_float2(c2, -s2);
    }
#pragma unroll
    for (int sb = 0; sb < 5; ++sb) {
      const int h = 1 << sb;
      const int e = (ll & (h - 1)) * (64 >> sb);
      const float ce = cosf(k * (float)e), se = sinf(k * (float)e);
      const bool up = (ll >> sb) & 1;
      sg[sb] = up ? -1.0f : 1.0f;
      if (!INV) ts[sb] = up ? make_float2(ce, se) : make_float2(1.0f, 0.0f);
      else      ts[sb] = make_float2(ce, -se);
    }
  }

  __device__ __forceinline__ float2 bff(float2 c, int sb) {
    float2 p = shflx(c, 1 << sb);
    float2 t = make_float2(fmaf(c.x, sg[sb], p.x), fmaf(c.y, sg[sb], p.y));
    return cmul(t, ts[sb]);
  }
  __device__ __forceinline__ float2 bfi(float2 c, int sb) {
    float2 p = shflx(c, 1 << sb);
    const bool up = (ll >> sb) & 1;
    float2 src = up ? c : p;
    float2 m = cmul(src, ts[sb]);
    float2 base = up ? p : c;
    return make_float2(fmaf(m.x, sg[sb], base.x), fmaf(m.y, sg[sb], base.y));
  }

  __device__ void run(float2& c0, float2& c1, float2& c2, float2& c3) {
    if (!INV) {
      float2 d0 = f2sub(c0, c2), d1 = f2sub(c1, c3);
      c0 = f2add(c0, c2); c1 = f2add(c1, c3);
      c2 = cmul(d0, wA);  c3 = cmul(d1, wB);
      float2 e0 = f2sub(c0, c1), e1 = f2sub(c2, c3);
      c0 = f2add(c0, c1); c1 = cmul(e0, w32);
      c2 = f2add(c2, c3); c3 = cmul(e1, w32);
#pragma unroll
      for (int sb = 4; sb >= 0; --sb) {
        c0 = bff(c0, sb); c1 = bff(c1, sb); c2 = bff(c2, sb); c3 = bff(c3, sb);
      }
    } else {
#pragma unroll
      for (int sb = 0; sb < 5; ++sb) {
        c0 = bfi(c0, sb); c1 = bfi(c1, sb); c2 = bfi(c2, sb); c3 = bfi(c3, sb);
      }
      float2 t, n;
      t = cmul(c1, w32); n = f2add(c0, t); c1 = f2sub(c0, t); c0 = n;
      t = cmul(c3, w32); n = f2add(c2, t); c3 = f2sub(c2, t); c2 = n;
      t = cmul(c2, wA);  n = f2add(c0, t); c2 = f2sub(c0, t); c0 = n;
      t = cmul(c3, wB);  n = f2add(c1, t); c3 = f2sub(c1, t); c1 = n;
    }
  }
};

// Forward 64-pt DIF: 16 lanes/line, lane l holds {l, l+16, l+32, l+48}.
// Radix-4 head in-lane, 4 cross stages (mask<=8). natural->bitrev6.
struct WF64F {
  float2 wA, wB, w32, ts[4];
  float  sg[4];

  __device__ void init(int l16) {
    const float k = -6.28318530717958647692f / 64.0f;
    const float ca = cosf(k * (float)l16), sa = sinf(k * (float)l16);
    const float c2 = cosf(k * (float)(2 * l16)), s2 = sinf(k * (float)(2 * l16));
    wA = make_float2(ca, sa);            // W64^l
    wB = make_float2(sa, -ca);           // W64^l * (-i)
    w32 = make_float2(c2, s2);           // W32^l
#pragma unroll
    for (int sb = 0; sb < 4; ++sb) {
      const int h = 1 << sb;
      const int e = (l16 & (h - 1)) * (32 >> sb);   // power of W64
      const float ce = cosf(k * (float)e), se = sinf(k * (float)e);
      const bool up = (l16 >> sb) & 1;
      sg[sb] = up ? -1.0f : 1.0f;
      ts[sb] = up ? make_float2(ce, se) : make_float2(1.0f, 0.0f);
    }
  }
  __device__ __forceinline__ float2 bff(float2 c, int sb) {
    float2 p = shflx(c, 1 << sb);
    float2 t = make_float2(fmaf(c.x, sg[sb], p.x), fmaf(c.y, sg[sb], p.y));
    return cmul(t, ts[sb]);
  }
  __device__ void run(float2& c0, float2& c1, float2& c2, float2& c3) {
    float2 d0 = f2sub(c0, c2), d1 = f2sub(c1, c3);
    c0 = f2add(c0, c2); c1 = f2add(c1, c3);
    c2 = cmul(d0, wA);  c3 = cmul(d1, wB);
    float2 e0 = f2sub(c0, c1), e1 = f2sub(c2, c3);
    c0 = f2add(c0, c1); c1 = cmul(e0, w32);
    c2 = f2add(c2, c3); c3 = cmul(e1, w32);
#pragma unroll
    for (int sb = 3; sb >= 0; --sb) {
      c0 = bff(c0, sb); c1 = bff(c1, sb); c2 = bff(c2, sb); c3 = bff(c3, sb);
    }
  }
};

// K1: block (b, z1, xh). Stage-1 split: xh=0 rows u=a[i]+a[i+64], xh=1 rows
// v=(a[i]-a[i+64])*W128^i; 64-pt x-FFT per row into LDS half-plane; 128-pt
// y-FFT down columns; write Z(b, x=64*xh+j, z1, y) (y-contiguous).
__global__ __launch_bounds__(1024, 8) void k_fwd_xy(const float* __restrict__ v1,
                                                    const float* __restrict__ v2,
                                                    float2* __restrict__ Z) {
  __shared__ float2 s[V * 65];
  const int tid = threadIdx.x, lane = tid & 63, wave = tid >> 6;
  const int ll2 = lane & 15, line = lane >> 4;
  const int xh = blockIdx.x & 1, bz = blockIdx.x >> 1;
  const int b = bz >> 7, z1 = bz & 127;
  const size_t ibase = (size_t)b * V3 + (size_t)z1 * V2;
  {
    WF64F F;
    F.init(ll2);
    float2 wk[4];
    if (xh) {
      const float kk = -6.28318530717958647692f / 128.0f;
#pragma unroll
      for (int k = 0; k < 4; ++k) {
        const float a = kk * (float)(ll2 + 16 * k);
        wk[k] = make_float2(cosf(a), sinf(a));
      }
    }
#pragma unroll
    for (int it = 0; it < 2; ++it) {
      const int y = it * 64 + wave * 4 + line;
      const size_t g = ibase + (size_t)y * V;
      float2 c[4];
#pragma unroll
      for (int k = 0; k < 4; ++k) {
        const int i = ll2 + 16 * k;
        float2 lo = make_float2(v1[g + i],      v2[g + i]);
        float2 hi = make_float2(v1[g + 64 + i], v2[g + 64 + i]);
        c[k] = xh ? cmul(f2sub(lo, hi), wk[k]) : f2add(lo, hi);
      }
      F.run(c[0], c[1], c[2], c[3]);
#pragma unroll
      for (int k = 0; k < 4; ++k) s[y * 65 + ll2 + 16 * k] = c[k];
    }
  }
  __syncthreads();
  const int ll = lane & 31, half = lane >> 5;
  WF128<false> G;
  G.init(lane);
#pragma unroll
  for (int it = 0; it < 2; ++it) {
    const int j = it * 32 + wave * 2 + half;
    float2 c0 = s[ll * 65 + j];
    float2 c1 = s[(32 + ll) * 65 + j];
    float2 c2 = s[(64 + ll) * 65 + j];
    float2 c3 = s[(96 + ll) * 65 + j];
    G.run(c0, c1, c2, c3);
    const size_t zb = ((size_t)(b * V + 64 * xh + j) * V + z1) * V;
    Z[zb + ll] = c0;       Z[zb + 32 + ll] = c1;
    Z[zb + 64 + ll] = c2;  Z[zb + 96 + ll] = c3;
  }
}

// K2: fused fwd-z + combine + inv-z on quarter tiles. Block r in [0,258):
// r<252: x-pair pg=r>>2, A-quarter qa=r&3, B-quarter img(qa);
// r>=252: x in {0,1}, qa in {0,1} single-tile, qa=2 pairs quarters 2&3.
__global__ __launch_bounds__(1024, 8) void k_z_fused(float2* __restrict__ Z) {
  __shared__ float2 T[2 * TILEQ];
  const int tid = threadIdx.x, lane = tid & 63, wave = tid >> 6;
  const int ll = lane & 31, half = lane >> 5;
  const int blk = blockIdx.x;
  const int b = blk / 258, r = blk % 258;
  int xA, xB, qa, qb;
  if (r < 252) {
    const int pg = r >> 2;
    qa = r & 3;
    int cnt = pg, j;
    for (j = 0; j < 128; ++j) {
      if (j < negrev(j)) {
        if (cnt == 0) break;
        --cnt;
      }
    }
    xA = j; xB = negrev(j);
  } else {
    const int r2 = r - 252;
    xA = xB = r2 / 3;
    qa = r2 % 3;
  }
  qb = (qa < 2) ? qa : (5 - qa);   // img: 0->0, 1->1, 2->3
  const bool single = (xA == xB) && (qa == qb);
  const size_t baseA = (size_t)(b * V + xA) * V2 + 32 * qa;
  const size_t baseB = (size_t)(b * V + xB) * V2 + 32 * qb;

  for (int p = tid; p < 4096; p += 1024) {
    const int z = p >> 5, ly = p & 31;
    T[z * PQ + ly] = Z[baseA + (size_t)z * V + ly];
  }
  if (!single) {
    for (int p = tid; p < 4096; p += 1024) {
      const int z = p >> 5, ly = p & 31;
      T[TILEQ + z * PQ + ly] = Z[baseB + (size_t)z * V + ly];
    }
  }
  __syncthreads();

  const int ncol = single ? 32 : 64;
  {
    WF128<false> Ff;
    Ff.init(lane);
    for (int cc = wave * 2 + half; cc < ncol; cc += 32) {
      const int tb = (cc >> 5) * TILEQ, ly = cc & 31;
      float2 c0 = T[tb + ll * PQ + ly];
      float2 c1 = T[tb + (32 + ll) * PQ + ly];
      float2 c2 = T[tb + (64 + ll) * PQ + ly];
      float2 c3 = T[tb + (96 + ll) * PQ + ly];
      Ff.run(c0, c1, c2, c3);
      T[tb + ll * PQ + ly] = c0;        T[tb + (32 + ll) * PQ + ly] = c1;
      T[tb + (64 + ll) * PQ + ly] = c2; T[tb + (96 + ll) * PQ + ly] = c3;
    }
  }
  __syncthreads();

  if (!single) {
    for (int p = tid; p < 4096; p += 1024) {
      const int z = p >> 5, ly = p & 31;
      const int zm = negrev(z), lyb = negrev(32 * qa + ly) & 31;
      const float2 a  = T[z * PQ + ly];
      const float2 bb = T[TILEQ + zm * PQ + lyb];
      const float f1r = 0.5f * (a.x + bb.x), f1i = 0.5f * (a.y - bb.y);
      const float f2r = 0.5f * (a.y + bb.y), f2i = 0.5f * (bb.x - a.x);
      const float gr = f1r * f2r + f1i * f2i;
      const float gi = f1i * f2r - f1r * f2i;
      T[z * PQ + ly] = make_float2(gr, gi);
      T[TILEQ + zm * PQ + lyb] = make_float2(gr, -gi);
    }
  } else {
    for (int p = tid; p < 4096; p += 1024) {
      const int z = p >> 5, ly = p & 31;
      const int zm = negrev(z), lym = negrev(32 * qa + ly) & 31;
      const int pm = zm * 32 + lym;
      if (pm < p) continue;
      const float2 a  = T[z * PQ + ly];
      const float2 bb = T[zm * PQ + lym];
      const float f1r = 0.5f * (a.x + bb.x), f1i = 0.5f * (a.y - bb.y);
      const float f2r = 0.5f * (a.y + bb.y), f2i = 0.5f * (bb.x - a.x);
      const float gr = f1r * f2r + f1i * f2i;
      const float gi = f1i * f2r - f1r * f2i;
      T[z * PQ + ly] = make_float2(gr, gi);
      if (pm != p) T[zm * PQ + lym] = make_float2(gr, -gi);
    }
  }
  __syncthreads();

  {
    WF128<true> Fi;
    Fi.init(lane);
    for (int cc = wave * 2 + half; cc < ncol; cc += 32) {
      const int tb = (cc >> 5) * TILEQ, ly = cc & 31;
      float2 c0 = T[tb + ll * PQ + ly];
      float2 c1 = T[tb + (32 + ll) * PQ + ly];
      float2 c2 = T[tb + (64 + ll) * PQ + ly];
      float2 c3 = T[tb + (96 + ll) * PQ + ly];
      Fi.run(c0, c1, c2, c3);
      T[tb + ll * PQ + ly] = c0;        T[tb + (32 + ll) * PQ + ly] = c1;
      T[tb + (64 + ll) * PQ + ly] = c2; T[tb + (96 + ll) * PQ + ly] = c3;
    }
  }
  __syncthreads();

  for (int p = tid; p < 4096; p += 1024) {
    const int z = p >> 5, ly = p & 31;
    Z[baseA + (size_t)z * V + ly] = T[z * PQ + ly];
  }
  if (!single) {
    for (int p = tid; p < 4096; p += 1024) {
      const int z = p >> 5, ly = p & 31;
      Z[baseB + (size_t)z * V + ly] = T[TILEQ + z * PQ + ly];
    }
  }
}

// K3: block (b, zp) packs planes z=zp and z=zp+64: P = Wa + i*Wb; one
// complex 2D inverse; Re -> out plane zp, Im -> out plane zp+64.
__global__ __launch_bounds__(1024) void k_inv_xy(const float2* __restrict__ Z,
                                                 float* __restrict__ out) {
  __shared__ float2 s[V * 129];
  const int tid = threadIdx.x, lane = tid & 63, wave = tid >> 6;
  const int ll = lane & 31, half = lane >> 5;
  const int b = blockIdx.x >> 6, zp = blockIdx.x & 63;
  const int za = zp, zb_ = zp + 64;
  WF128<true> F;
  F.init(lane);
#pragma unroll 2
  for (int it = 0; it < 4; ++it) {
    const int x = it * 32 + wave * 2 + half;
    const size_t ca = (size_t)(b * V + x) * V2 + (size_t)za * V;
    const size_t cb = (size_t)(b * V + x) * V2 + (size_t)zb_ * V;
    float2 c[4];
#pragma unroll
    for (int m = 0; m < 4; ++m) {
      const float2 A  = Z[ca + ll + 32 * m];
      const float2 Bv = Z[cb + ll + 32 * m];
      c[m] = make_float2(A.x - Bv.y, A.y + Bv.x);   // Wa + i*Wb
    }
    F.run(c[0], c[1], c[2], c[3]);
#pragma unroll
    for (int m = 0; m < 4; ++m) s[(ll + 32 * m) * 129 + x] = c[m];
  }
  __syncthreads();
  const float sc = 1.0f / 2097152.0f;  // 1/V^3
  const size_t oa = (size_t)b * V3 + (size_t)za * V2;
  const size_t ob = (size_t)b * V3 + (size_t)zb_ * V2;
#pragma unroll 2
  for (int it = 0; it < 4; ++it) {
    const int y = it * 32 + wave * 2 + half;
    float2 c0 = s[y * 129 + ll];
    float2 c1 = s[y * 129 + 32 + ll];
    float2 c2 = s[y * 129 + 64 + ll];
    float2 c3 = s[y * 129 + 96 + ll];
    F.run(c0, c1, c2, c3);
    const size_t ga = oa + (size_t)y * V;
    const size_t gb = ob + (size_t)y * V;
    out[ga + ll] = c0.x * sc;       out[gb + ll] = c0.y * sc;
    out[ga + 32 + ll] = c1.x * sc;  out[gb + 32 + ll] = c1.y * sc;
    out[ga + 64 + ll] = c2.x * sc;  out[gb + 64 + ll] = c2.y * sc;
    out[ga + 96 + ll] = c3.x * sc;  out[gb + 96 + ll] = c3.y * sc;
  }
}

extern "C" void kernel_launch(void* const* d_in, const int* in_sizes, int n_in,
                              void* d_out, int out_size, void* d_ws, size_t ws_size,
                              hipStream_t stream) {
  const float* v1 = (const float*)d_in[0];
  const float* v2 = (const float*)d_in[1];
  float* out = (float*)d_out;
  float2* Z  = (float2*)d_ws;  // NB*V3*8 = 128 MiB

  k_fwd_xy<<<NB * V * 2, 1024, 0, stream>>>(v1, v2, Z);   // (b, z1, xh)
  k_z_fused<<<NB * 258, 1024, 0, stream>>>(Z);            // (b, pair/quarter)
  k_inv_xy<<<NB * 64, 1024, 0, stream>>>(Z, out);         // (b, plane-pair)
}